// Round 2
// baseline (102.495 us; speedup 1.0000x reference)
//
#include <hip/hip_runtime.h>

// Problem constants (from the reference file)
#define GN_NODES   1000000
#define GN_TPB     256
#define GN_NBLOCKS 1024

// ws layout: float sums[5]; unsigned int counter;  (zeroed by memset each call)

__global__ __launch_bounds__(GN_TPB) void gn_fused(
    const float* __restrict__ cart,
    const float* __restrict__ neigh,
    const float* __restrict__ Wc1,  const float* __restrict__ bc1,
    const float* __restrict__ Wc2,  const float* __restrict__ bc2,
    const float* __restrict__ Wn1,  const float* __restrict__ bn1,
    const float* __restrict__ Wn2,  const float* __restrict__ bn2,
    const float* __restrict__ Wcomb, const float* __restrict__ bcomb,
    const float* __restrict__ Wdeco, const float* __restrict__ bdeco,
    const int* __restrict__ kptr,
    float* __restrict__ ws,
    float* __restrict__ out)
{
    const int tid = blockIdx.x * GN_TPB + threadIdx.x;
    const int T   = GN_NBLOCKS * GN_TPB;

    float sx = 0.f, sy = 0.f, sz = 0.f, s0 = 0.f, s1 = 0.f;

    // cart: 3,000,000 floats = 250,000 chunks of 12 floats (4 nodes).
    // Component pattern within a chunk: x y z x y z x y z x y z.
    const float4* cart4 = reinterpret_cast<const float4*>(cart);
    for (int c = tid; c < 250000; c += T) {
        float4 a = cart4[3 * c + 0];
        float4 b = cart4[3 * c + 1];
        float4 d = cart4[3 * c + 2];
        sx += a.x + a.w + b.z + d.y;
        sy += a.y + b.x + b.w + d.z;
        sz += a.z + b.y + d.x + d.w;
    }

    // neigh: 8,000,000 floats = 2,000,000 float4; components alternate 0,1,0,1.
    // Unrolled x2 for more outstanding loads.
    const float4* n4 = reinterpret_cast<const float4*>(neigh);
    int i = tid;
    for (; i + T < 2000000; i += 2 * T) {
        float4 v = n4[i];
        float4 w = n4[i + T];
        s0 += (v.x + v.z) + (w.x + w.z);
        s1 += (v.y + v.w) + (w.y + w.w);
    }
    if (i < 2000000) {
        float4 v = n4[i];
        s0 += v.x + v.z;
        s1 += v.y + v.w;
    }

    // Wave (64-lane) reduce.
    for (int o = 32; o > 0; o >>= 1) {
        sx += __shfl_down(sx, o);
        sy += __shfl_down(sy, o);
        sz += __shfl_down(sz, o);
        s0 += __shfl_down(s0, o);
        s1 += __shfl_down(s1, o);
    }

    __shared__ float red[5][GN_TPB / 64];
    const int wave = threadIdx.x >> 6;
    if ((threadIdx.x & 63) == 0) {
        red[0][wave] = sx; red[1][wave] = sy; red[2][wave] = sz;
        red[3][wave] = s0; red[4][wave] = s1;
    }
    __syncthreads();

    if (threadIdx.x == 0) {
        float t[5];
        #pragma unroll
        for (int c = 0; c < 5; ++c)
            t[c] = red[c][0] + red[c][1] + red[c][2] + red[c][3];
        #pragma unroll
        for (int c = 0; c < 5; ++c)
            atomicAdd(&ws[c], t[c]);
        __threadfence();

        unsigned int* counter = reinterpret_cast<unsigned int*>(ws + 5);
        unsigned int old = atomicAdd(counter, 1u);
        if (old == (unsigned int)(gridDim.x - 1)) {
            // Last block: totals are complete and visible (device-scope atomics).
            double tot[5];
            #pragma unroll
            for (int c = 0; c < 5; ++c)
                tot[c] = (double)__hip_atomic_load(&ws[c], __ATOMIC_RELAXED,
                                                   __HIP_MEMORY_SCOPE_AGENT);

            const double NN  = (double)GN_NODES;
            const double Sc0 = tot[0], Sc1 = tot[1], Sc2 = tot[2];
            const double Sn0 = tot[3], Sn1 = tot[4];

            // H = sum_nodes of (cart @ Wc1^T + bc1) @ Wc2^T + bc2
            double tt[10], H[10];
            for (int p = 0; p < 10; ++p)
                tt[p] = (double)Wc1[p*3+0]*Sc0 + (double)Wc1[p*3+1]*Sc1 +
                        (double)Wc1[p*3+2]*Sc2 + NN*(double)bc1[p];
            for (int q = 0; q < 10; ++q) {
                double s = NN * (double)bc2[q];
                for (int p = 0; p < 10; ++p) s += (double)Wc2[q*10+p] * tt[p];
                H[q] = s;
            }

            // Mv = sum_nodes of mean_j (neigh @ Wn1^T + bn1) @ Wn2^T + bn2
            double u[10], Mv[10];
            for (int p = 0; p < 10; ++p)
                u[p] = (double)Wn1[p*2+0]*(Sn0*0.25) +
                       (double)Wn1[p*2+1]*(Sn1*0.25) + NN*(double)bn1[p];
            for (int q = 0; q < 10; ++q) {
                double s = NN * (double)bn2[q];
                for (int p = 0; p < 10; ++p) s += (double)Wn2[q*10+p] * u[p];
                Mv[q] = s;
            }

            // k rounds of comb on the summed state
            const int k = *kptr;
            double S[10], C[10];
            for (int q = 0; q < 10; ++q) S[q] = H[q];
            for (int it = 0; it < k; ++it) {
                for (int q = 0; q < 10; ++q) {
                    double s = NN * (double)bcomb[q];
                    for (int p = 0; p < 10; ++p) {
                        s += (double)Wcomb[q*20 + p]      * Mv[p];
                        s += (double)Wcomb[q*20 + 10 + p] * S[p];
                    }
                    C[q] = s;
                }
                for (int q = 0; q < 10; ++q) S[q] = C[q];
            }

            // decode
            double o = (double)bdeco[0];
            for (int q = 0; q < 10; ++q) o += (double)Wdeco[q] * S[q];
            out[0] = (float)o;
        }
    }
}

extern "C" void kernel_launch(void* const* d_in, const int* in_sizes, int n_in,
                              void* d_out, int out_size, void* d_ws, size_t ws_size,
                              hipStream_t stream) {
    const float* cart  = (const float*)d_in[0];
    const float* neigh = (const float*)d_in[1];
    const float* Wc1   = (const float*)d_in[2];
    const float* bc1   = (const float*)d_in[3];
    const float* Wc2   = (const float*)d_in[4];
    const float* bc2   = (const float*)d_in[5];
    const float* Wn1   = (const float*)d_in[6];
    const float* bn1   = (const float*)d_in[7];
    const float* Wn2   = (const float*)d_in[8];
    const float* bn2   = (const float*)d_in[9];
    const float* Wcomb = (const float*)d_in[10];
    const float* bcomb = (const float*)d_in[11];
    const float* Wdeco = (const float*)d_in[12];
    const float* bdeco = (const float*)d_in[13];
    const int*   kptr  = (const int*)d_in[14];

    // Zero the 5 accumulators + counter (deterministic start each call).
    hipMemsetAsync(d_ws, 0, 64, stream);

    gn_fused<<<GN_NBLOCKS, GN_TPB, 0, stream>>>(
        cart, neigh,
        Wc1, bc1, Wc2, bc2, Wn1, bn1, Wn2, bn2,
        Wcomb, bcomb, Wdeco, bdeco, kptr,
        (float*)d_ws, (float*)d_out);
}

// Round 3
// 58.633 us; speedup vs baseline: 1.7481x; 1.7481x over previous
//
#include <hip/hip_runtime.h>

// Problem constants (from the reference file)
#define GN_NODES   1000000
#define GN_TPB     256
#define GN_NBLOCKS 1024

// ws layout (floats): sum c at ws[c*16] (64B apart, c=0..4); counter at ws[96].
// Zeroed by a 512B hipMemsetAsync each call (deterministic start).

__global__ __launch_bounds__(GN_TPB, 4) void gn_fused(
    const float* __restrict__ cart,
    const float* __restrict__ neigh,
    const float* __restrict__ Wc1,  const float* __restrict__ bc1,
    const float* __restrict__ Wc2,  const float* __restrict__ bc2,
    const float* __restrict__ Wn1,  const float* __restrict__ bn1,
    const float* __restrict__ Wn2,  const float* __restrict__ bn2,
    const float* __restrict__ Wcomb, const float* __restrict__ bcomb,
    const float* __restrict__ Wdeco, const float* __restrict__ bdeco,
    const int* __restrict__ kptr,
    float* __restrict__ ws,
    float* __restrict__ out)
{
    const int tid = blockIdx.x * GN_TPB + threadIdx.x;
    const int T   = GN_NBLOCKS * GN_TPB;

    float sx = 0.f, sy = 0.f, sz = 0.f, s0 = 0.f, s1 = 0.f;

    // cart: 3,000,000 floats = 250,000 chunks of 12 floats (4 nodes).
    // Component pattern within a chunk: x y z x y z x y z x y z.
    const float4* cart4 = reinterpret_cast<const float4*>(cart);
    for (int c = tid; c < 250000; c += T) {
        float4 a = cart4[3 * c + 0];
        float4 b = cart4[3 * c + 1];
        float4 d = cart4[3 * c + 2];
        sx += a.x + a.w + b.z + d.y;
        sy += a.y + b.x + b.w + d.z;
        sz += a.z + b.y + d.x + d.w;
    }

    // neigh: 8,000,000 floats = 2,000,000 float4; components alternate 0,1,0,1.
    const float4* n4 = reinterpret_cast<const float4*>(neigh);
    int i = tid;
    for (; i + T < 2000000; i += 2 * T) {
        float4 v = n4[i];
        float4 w = n4[i + T];
        s0 += (v.x + v.z) + (w.x + w.z);
        s1 += (v.y + v.w) + (w.y + w.w);
    }
    if (i < 2000000) {
        float4 v = n4[i];
        s0 += v.x + v.z;
        s1 += v.y + v.w;
    }

    // Wave (64-lane) reduce.
    for (int o = 32; o > 0; o >>= 1) {
        sx += __shfl_down(sx, o);
        sy += __shfl_down(sy, o);
        sz += __shfl_down(sz, o);
        s0 += __shfl_down(s0, o);
        s1 += __shfl_down(s1, o);
    }

    __shared__ float red[5][GN_TPB / 64];
    __shared__ int lastFlag;
    const int wave = threadIdx.x >> 6;
    if ((threadIdx.x & 63) == 0) {
        red[0][wave] = sx; red[1][wave] = sy; red[2][wave] = sz;
        red[3][wave] = s0; red[4][wave] = s1;
    }
    __syncthreads();

    if (threadIdx.x == 0) {
        #pragma unroll
        for (int c = 0; c < 5; ++c) {
            float t = red[c][0] + red[c][1] + red[c][2] + red[c][3];
            atomicAdd(&ws[c * 16], t);   // device-coherent, no fence needed
        }
        // Ensure THIS block's atomics reached the coherent point before the
        // counter increment (no L2-writeback fence — atomics don't dirty L2).
        asm volatile("s_waitcnt vmcnt(0)" ::: "memory");
        unsigned int* counter = reinterpret_cast<unsigned int*>(ws + 96);
        unsigned int old = __hip_atomic_fetch_add(
            counter, 1u, __ATOMIC_RELAXED, __HIP_MEMORY_SCOPE_AGENT);
        lastFlag = (old == (unsigned int)(GN_NBLOCKS - 1)) ? 1 : 0;
    }
    __syncthreads();

    if (lastFlag) {
        // Last block: stage all weights into LDS cooperatively (parallel
        // latency instead of ~500 serial scalar loads), then thread 0 runs
        // the tiny affine network in fp32.
        __shared__ float wbuf[512];
        __shared__ int kk;
        const int t = threadIdx.x;
        for (int j = t; j <  30; j += GN_TPB) wbuf[  0 + j] = Wc1[j];
        for (int j = t; j <  10; j += GN_TPB) wbuf[ 30 + j] = bc1[j];
        for (int j = t; j < 100; j += GN_TPB) wbuf[ 40 + j] = Wc2[j];
        for (int j = t; j <  10; j += GN_TPB) wbuf[140 + j] = bc2[j];
        for (int j = t; j <  20; j += GN_TPB) wbuf[150 + j] = Wn1[j];
        for (int j = t; j <  10; j += GN_TPB) wbuf[170 + j] = bn1[j];
        for (int j = t; j < 100; j += GN_TPB) wbuf[180 + j] = Wn2[j];
        for (int j = t; j <  10; j += GN_TPB) wbuf[280 + j] = bn2[j];
        for (int j = t; j < 200; j += GN_TPB) wbuf[290 + j] = Wcomb[j];
        for (int j = t; j <  10; j += GN_TPB) wbuf[490 + j] = bcomb[j];
        for (int j = t; j <  10; j += GN_TPB) wbuf[500 + j] = Wdeco[j];
        if (t == 0) wbuf[510] = bdeco[0];
        if (t == 1) kk = *kptr;
        __syncthreads();

        if (t == 0) {
            float tot[5];
            #pragma unroll
            for (int c = 0; c < 5; ++c)
                tot[c] = __hip_atomic_load(&ws[c * 16], __ATOMIC_RELAXED,
                                           __HIP_MEMORY_SCOPE_AGENT);
            const float NN = 1.0e6f;
            const float Sc0 = tot[0], Sc1 = tot[1], Sc2 = tot[2];
            const float Sn0 = tot[3], Sn1 = tot[4];

            const float* WC1 = wbuf +   0; const float* BC1 = wbuf +  30;
            const float* WC2 = wbuf +  40; const float* BC2 = wbuf + 140;
            const float* WN1 = wbuf + 150; const float* BN1 = wbuf + 170;
            const float* WN2 = wbuf + 180; const float* BN2 = wbuf + 280;
            const float* WCB = wbuf + 290; const float* BCB = wbuf + 490;
            const float* WDE = wbuf + 500; const float  BDE = wbuf[510];

            // H = sum_nodes of (cart @ Wc1^T + bc1) @ Wc2^T + bc2
            float tt[10], H[10];
            #pragma unroll
            for (int p = 0; p < 10; ++p)
                tt[p] = WC1[p*3+0]*Sc0 + WC1[p*3+1]*Sc1 + WC1[p*3+2]*Sc2
                      + NN * BC1[p];
            #pragma unroll
            for (int q = 0; q < 10; ++q) {
                float s = NN * BC2[q];
                #pragma unroll
                for (int p = 0; p < 10; ++p) s += WC2[q*10+p] * tt[p];
                H[q] = s;
            }

            // Mv = sum_nodes of mean_j (neigh @ Wn1^T + bn1) @ Wn2^T + bn2
            float u[10], Mv[10];
            #pragma unroll
            for (int p = 0; p < 10; ++p)
                u[p] = WN1[p*2+0]*(Sn0*0.25f) + WN1[p*2+1]*(Sn1*0.25f)
                     + NN * BN1[p];
            #pragma unroll
            for (int q = 0; q < 10; ++q) {
                float s = NN * BN2[q];
                #pragma unroll
                for (int p = 0; p < 10; ++p) s += WN2[q*10+p] * u[p];
                Mv[q] = s;
            }

            // k rounds of comb on the summed state
            float S[10], C[10];
            #pragma unroll
            for (int q = 0; q < 10; ++q) S[q] = H[q];
            for (int it = 0; it < kk; ++it) {
                #pragma unroll
                for (int q = 0; q < 10; ++q) {
                    float s = NN * BCB[q];
                    #pragma unroll
                    for (int p = 0; p < 10; ++p) {
                        s += WCB[q*20 + p]      * Mv[p];
                        s += WCB[q*20 + 10 + p] * S[p];
                    }
                    C[q] = s;
                }
                #pragma unroll
                for (int q = 0; q < 10; ++q) S[q] = C[q];
            }

            // decode
            float o = BDE;
            #pragma unroll
            for (int q = 0; q < 10; ++q) o += WDE[q] * S[q];
            out[0] = o;
        }
    }
}

extern "C" void kernel_launch(void* const* d_in, const int* in_sizes, int n_in,
                              void* d_out, int out_size, void* d_ws, size_t ws_size,
                              hipStream_t stream) {
    const float* cart  = (const float*)d_in[0];
    const float* neigh = (const float*)d_in[1];
    const float* Wc1   = (const float*)d_in[2];
    const float* bc1   = (const float*)d_in[3];
    const float* Wc2   = (const float*)d_in[4];
    const float* bc2   = (const float*)d_in[5];
    const float* Wn1   = (const float*)d_in[6];
    const float* bn1   = (const float*)d_in[7];
    const float* Wn2   = (const float*)d_in[8];
    const float* bn2   = (const float*)d_in[9];
    const float* Wcomb = (const float*)d_in[10];
    const float* bcomb = (const float*)d_in[11];
    const float* Wdeco = (const float*)d_in[12];
    const float* bdeco = (const float*)d_in[13];
    const int*   kptr  = (const int*)d_in[14];

    // Zero accumulators + counter (512 B covers ws[0..96]).
    hipMemsetAsync(d_ws, 0, 512, stream);

    gn_fused<<<GN_NBLOCKS, GN_TPB, 0, stream>>>(
        cart, neigh,
        Wc1, bc1, Wc2, bc2, Wn1, bn1, Wn2, bn2,
        Wcomb, bcomb, Wdeco, bdeco, kptr,
        (float*)d_ws, (float*)d_out);
}

// Round 4
// 26.638 us; speedup vs baseline: 3.8477x; 2.2011x over previous
//
#include <hip/hip_runtime.h>

// Problem constants (from the reference file)
#define GN_NODES   1000000
#define GN_TPB     1024
#define GN_NBLOCKS 256
#define GN_T       (GN_TPB * GN_NBLOCKS)   // 262144 threads total

// Fully-linear network: out = sum_b f_beta(S_b), where S_b are block-partial
// input sums and beta carries the bias terms (1e6 on block 0 only, 0 elsewhere).
// Each block contributes ONE float atomicAdd to out[0] (zeroed by memset).
// No counter, no fences, no cross-block reads -> no RMW serialization tail.

__global__ __launch_bounds__(GN_TPB) void gn_fused(
    const float* __restrict__ cart,
    const float* __restrict__ neigh,
    const float* __restrict__ Wc1,  const float* __restrict__ bc1,
    const float* __restrict__ Wc2,  const float* __restrict__ bc2,
    const float* __restrict__ Wn1,  const float* __restrict__ bn1,
    const float* __restrict__ Wn2,  const float* __restrict__ bn2,
    const float* __restrict__ Wcomb, const float* __restrict__ bcomb,
    const float* __restrict__ Wdeco, const float* __restrict__ bdeco,
    const int* __restrict__ kptr,
    float* __restrict__ out)
{
    const int tid = blockIdx.x * GN_TPB + threadIdx.x;

    float sx = 0.f, sy = 0.f, sz = 0.f, s0 = 0.f, s1 = 0.f;

    // cart: 3,000,000 floats = 250,000 chunks of 12 floats (4 nodes).
    // Component pattern within a chunk: x y z x y z x y z x y z.
    const float4* cart4 = reinterpret_cast<const float4*>(cart);
    for (int c = tid; c < 250000; c += GN_T) {
        float4 a = cart4[3 * c + 0];
        float4 b = cart4[3 * c + 1];
        float4 d = cart4[3 * c + 2];
        sx += a.x + a.w + b.z + d.y;
        sy += a.y + b.x + b.w + d.z;
        sz += a.z + b.y + d.x + d.w;
    }

    // neigh: 8,000,000 floats = 2,000,000 float4; components alternate 0,1,0,1.
    const float4* n4 = reinterpret_cast<const float4*>(neigh);
    int i = tid;
    for (; i + GN_T < 2000000; i += 2 * GN_T) {
        float4 v = n4[i];
        float4 w = n4[i + GN_T];
        s0 += (v.x + v.z) + (w.x + w.z);
        s1 += (v.y + v.w) + (w.y + w.w);
    }
    if (i < 2000000) {
        float4 v = n4[i];
        s0 += v.x + v.z;
        s1 += v.y + v.w;
    }

    // Wave (64-lane) reduce.
    for (int o = 32; o > 0; o >>= 1) {
        sx += __shfl_down(sx, o);
        sy += __shfl_down(sy, o);
        sz += __shfl_down(sz, o);
        s0 += __shfl_down(s0, o);
        s1 += __shfl_down(s1, o);
    }

    __shared__ float red[5][GN_TPB / 64];
    const int wave = threadIdx.x >> 6;
    if ((threadIdx.x & 63) == 0) {
        red[0][wave] = sx; red[1][wave] = sy; red[2][wave] = sz;
        red[3][wave] = s0; red[4][wave] = s1;
    }
    __syncthreads();

    if (threadIdx.x == 0) {
        float Sc0 = 0.f, Sc1 = 0.f, Sc2 = 0.f, Sn0 = 0.f, Sn1 = 0.f;
        #pragma unroll
        for (int w = 0; w < GN_TPB / 64; ++w) {
            Sc0 += red[0][w]; Sc1 += red[1][w]; Sc2 += red[2][w];
            Sn0 += red[3][w]; Sn1 += red[4][w];
        }

        // Bias factor: block 0 carries all NODES*bias terms; others are pure
        // linear. Sum over blocks == reference result (everything is affine).
        const float isb0 = (blockIdx.x == 0) ? 1.f : 0.f;
        const float beta = isb0 * 1.0e6f;

        // H_b = (Sc_b @ Wc1^T + beta*bc1) @ Wc2^T + beta*bc2
        float tt[10], H[10];
        #pragma unroll
        for (int p = 0; p < 10; ++p)
            tt[p] = Wc1[p*3+0]*Sc0 + Wc1[p*3+1]*Sc1 + Wc1[p*3+2]*Sc2
                  + beta * bc1[p];
        #pragma unroll
        for (int q = 0; q < 10; ++q) {
            float s = beta * bc2[q];
            #pragma unroll
            for (int p = 0; p < 10; ++p) s += Wc2[q*10+p] * tt[p];
            H[q] = s;
        }

        // Mv_b = (0.25*Sn_b @ Wn1^T + beta*bn1) @ Wn2^T + beta*bn2
        float u[10], Mv[10];
        #pragma unroll
        for (int p = 0; p < 10; ++p)
            u[p] = Wn1[p*2+0]*(Sn0*0.25f) + Wn1[p*2+1]*(Sn1*0.25f)
                 + beta * bn1[p];
        #pragma unroll
        for (int q = 0; q < 10; ++q) {
            float s = beta * bn2[q];
            #pragma unroll
            for (int p = 0; p < 10; ++p) s += Wn2[q*10+p] * u[p];
            Mv[q] = s;
        }

        // k comb rounds on the block-partial state.
        const int kk = *kptr;
        float S[10], C[10];
        #pragma unroll
        for (int q = 0; q < 10; ++q) S[q] = H[q];
        for (int it = 0; it < kk; ++it) {
            #pragma unroll
            for (int q = 0; q < 10; ++q) {
                float s = beta * bcomb[q];
                #pragma unroll
                for (int p = 0; p < 10; ++p) {
                    s += Wcomb[q*20 + p]      * Mv[p];
                    s += Wcomb[q*20 + 10 + p] * S[p];
                }
                C[q] = s;
            }
            #pragma unroll
            for (int q = 0; q < 10; ++q) S[q] = C[q];
        }

        // decode; bdeco only once (block 0).
        float o = isb0 * bdeco[0];
        #pragma unroll
        for (int q = 0; q < 10; ++q) o += Wdeco[q] * S[q];

        atomicAdd(out, o);   // one RMW per block, 256 total, staggered
    }
}

extern "C" void kernel_launch(void* const* d_in, const int* in_sizes, int n_in,
                              void* d_out, int out_size, void* d_ws, size_t ws_size,
                              hipStream_t stream) {
    const float* cart  = (const float*)d_in[0];
    const float* neigh = (const float*)d_in[1];
    const float* Wc1   = (const float*)d_in[2];
    const float* bc1   = (const float*)d_in[3];
    const float* Wc2   = (const float*)d_in[4];
    const float* bc2   = (const float*)d_in[5];
    const float* Wn1   = (const float*)d_in[6];
    const float* bn1   = (const float*)d_in[7];
    const float* Wn2   = (const float*)d_in[8];
    const float* bn2   = (const float*)d_in[9];
    const float* Wcomb = (const float*)d_in[10];
    const float* bcomb = (const float*)d_in[11];
    const float* Wdeco = (const float*)d_in[12];
    const float* bdeco = (const float*)d_in[13];
    const int*   kptr  = (const int*)d_in[14];

    // Zero the single output accumulator (deterministic start each call).
    hipMemsetAsync(d_out, 0, sizeof(float), stream);

    gn_fused<<<GN_NBLOCKS, GN_TPB, 0, stream>>>(
        cart, neigh,
        Wc1, bc1, Wc2, bc2, Wn1, bn1, Wn2, bn2,
        Wcomb, bcomb, Wdeco, bdeco, kptr,
        (float*)d_out);
}